// Round 2
// baseline (848.297 us; speedup 1.0000x reference)
//
#include <hip/hip_runtime.h>
#include <math.h>

#define EPSF 1e-8f
#define SINH_MAXF 11.090354888959125f
#define IMAGE_ALPHA 0.25f
#define TEXT_ALPHA (1.0f/0.6f)
#define LOGIT_SCALE (1.0f/0.07f)
#define ENTAIL_WEIGHT 0.2f
#define NCLS 151
#define NPAD 160
#define DIM 64

// ws float offsets
#define YT_OFF 16
#define XN_OFF (YT_OFF + NPAD)
#define AP_OFF (XN_OFF + NPAD)
#define BT_OFF 512   // bf16 protos [160][64] = 20480 B, 16B-aligned

typedef __attribute__((ext_vector_type(8))) short bf16x8;
typedef __attribute__((ext_vector_type(4))) float f32x4;

__device__ inline unsigned short f2bf(float f) {
    unsigned int u = __float_as_uint(f);
    return (unsigned short)((u + 0x7FFFu + ((u >> 16) & 1u)) >> 16);
}

__device__ inline float sel4(const float* a, int i) {
    return i == 0 ? a[0] : i == 1 ? a[1] : i == 2 ? a[2] : a[3];
}

__global__ void proto_kernel(const float* __restrict__ protos, float* __restrict__ ws) {
    int c = blockIdx.x, d = threadIdx.x;
    unsigned short* bt = (unsigned short*)(ws + BT_OFF);
    if (c >= NCLS) {
        bt[c * DIM + d] = 0;
        if (d == 0) { ws[YT_OFF + c] = 2e18f; ws[XN_OFF + c] = 1.f; ws[AP_OFF + c] = 0.f; }
        return;
    }
    float v = protos[c * DIM + d] * TEXT_ALPHA;
    float n2 = v * v;
    #pragma unroll
    for (int m = 32; m >= 1; m >>= 1) n2 += __shfl_xor(n2, m, 64);
    float rc = sqrtf(n2);
    float sh = sinhf(fminf(fmaxf(rc, EPSF), SINH_MAXF));
    float sc = sh / fmaxf(rc, EPSF);
    bt[c * DIM + d] = f2bf(sc * v);
    if (d == 0) {
        float xn = sc * rc;
        ws[YT_OFF + c] = sqrtf(1.f + xn * xn);
        ws[XN_OFF + c] = xn;
        float ai = 0.2f / (xn + EPSF);
        ai = fminf(fmaxf(ai, -1.f + EPSF), 1.f - EPSF);
        ws[AP_OFF + c] = asinf(ai);
    }
}

__global__ __launch_bounds__(256) void main_kernel(
    const float* __restrict__ feats, const int* __restrict__ labels,
    const unsigned char* __restrict__ mask, const float* __restrict__ wsro,
    float* acc)
{
    int wid = threadIdx.x >> 6, lane = threadIdx.x & 63;
    int cn = lane & 15;       // pixel-in-tile (A row) AND class-in-tile (B col)
    int g  = lane >> 4;       // k-quad / row-group
    int wavebase = (blockIdx.x * 4 + wid) * 16;
    int pix = wavebase + cn;

    // ---- A staging: lane holds pixel `cn`, dims [g*8, g*8+8) and [32+g*8, 32+g*8+8) ----
    const float4* fp = (const float4*)(feats + (size_t)pix * DIM + g * 8);
    float4 a0 = fp[0], a1 = fp[1], b0 = fp[8], b1 = fp[9];
    a0.x *= IMAGE_ALPHA; a0.y *= IMAGE_ALPHA; a0.z *= IMAGE_ALPHA; a0.w *= IMAGE_ALPHA;
    a1.x *= IMAGE_ALPHA; a1.y *= IMAGE_ALPHA; a1.z *= IMAGE_ALPHA; a1.w *= IMAGE_ALPHA;
    b0.x *= IMAGE_ALPHA; b0.y *= IMAGE_ALPHA; b0.z *= IMAGE_ALPHA; b0.w *= IMAGE_ALPHA;
    b1.x *= IMAGE_ALPHA; b1.y *= IMAGE_ALPHA; b1.z *= IMAGE_ALPHA; b1.w *= IMAGE_ALPHA;
    float n2 = a0.x*a0.x + a0.y*a0.y + a0.z*a0.z + a0.w*a0.w
             + a1.x*a1.x + a1.y*a1.y + a1.z*a1.z + a1.w*a1.w
             + b0.x*b0.x + b0.y*b0.y + b0.z*b0.z + b0.w*b0.w
             + b1.x*b1.x + b1.y*b1.y + b1.z*b1.z + b1.w*b1.w;
    n2 += __shfl_xor(n2, 16, 64);
    n2 += __shfl_xor(n2, 32, 64);     // all 4 owner-lanes of this pixel now have full n2
    float rc = sqrtf(n2);
    float sh = sinhf(fminf(fmaxf(rc, EPSF), SINH_MAXF));
    float sc = sh / fmaxf(rc, EPSF);
    float xnorm = sc * rc;
    float xt = sqrtf(fmaf(xnorm, xnorm, 1.f));   // image time coordinate

    bf16x8 aq0, aq1;
    aq0[0] = (short)f2bf(sc * a0.x); aq0[1] = (short)f2bf(sc * a0.y);
    aq0[2] = (short)f2bf(sc * a0.z); aq0[3] = (short)f2bf(sc * a0.w);
    aq0[4] = (short)f2bf(sc * a1.x); aq0[5] = (short)f2bf(sc * a1.y);
    aq0[6] = (short)f2bf(sc * a1.z); aq0[7] = (short)f2bf(sc * a1.w);
    aq1[0] = (short)f2bf(sc * b0.x); aq1[1] = (short)f2bf(sc * b0.y);
    aq1[2] = (short)f2bf(sc * b0.z); aq1[3] = (short)f2bf(sc * b0.w);
    aq1[4] = (short)f2bf(sc * b1.x); aq1[5] = (short)f2bf(sc * b1.y);
    aq1[6] = (short)f2bf(sc * b1.z); aq1[7] = (short)f2bf(sc * b1.w);

    // distribute per-row (C-layout rows r = g*4+reg) label & xt via shuffles
    int lab_own = labels[pix];
    float xtr[4]; int labr[4];
    #pragma unroll
    for (int r = 0; r < 4; r++) {
        xtr[r]  = __shfl(xt, g * 4 + r, 64);
        labr[r] = __shfl(lab_own, g * 4 + r, 64);
    }

    const uint4* bt = (const uint4*)(wsro + BT_OFF);
    const float* ytp = wsro + YT_OFF;
    float lg[10][4];
    float cxl_lab[4] = {0.f, 0.f, 0.f, 0.f};

    #pragma unroll
    for (int t = 0; t < 10; t++) {
        uint4 r0 = bt[(t * 16 + cn) * 8 + g];        // class t*16+cn, dims g*8..+7
        uint4 r1 = bt[(t * 16 + cn) * 8 + 4 + g];    // dims 32+g*8..+7
        bf16x8 bq0 = __builtin_bit_cast(bf16x8, r0);
        bf16x8 bq1 = __builtin_bit_cast(bf16x8, r1);
        f32x4 d = {0.f, 0.f, 0.f, 0.f};
        d = __builtin_amdgcn_mfma_f32_16x16x32_bf16(aq0, bq0, d, 0, 0, 0);
        d = __builtin_amdgcn_mfma_f32_16x16x32_bf16(aq1, bq1, d, 0, 0, 0);
        float yt = ytp[t * 16 + cn];
        int cls = t * 16 + cn;
        #pragma unroll
        for (int r = 0; r < 4; r++) {
            float cxl = fmaf(xtr[r], yt, -d[r]);     // x_time*y_time - dot
            if (labr[r] == cls) cxl_lab[r] = cxl;
            float z = fmaxf(cxl, 1.f + EPSF);
            float dist = __logf(z + sqrtf(fmaf(z, z, -1.f)));
            lg[t][r] = -LOGIT_SCALE * dist;
        }
    }

    // per-lane LSE over the 10 owned classes, then merge across the 16-lane row group
    float mx[4], ss[4];
    #pragma unroll
    for (int r = 0; r < 4; r++) {
        float m = lg[0][r];
        #pragma unroll
        for (int t = 1; t < 10; t++) m = fmaxf(m, lg[t][r]);
        float s = 0.f;
        #pragma unroll
        for (int t = 0; t < 10; t++) s += __expf(lg[t][r] - m);
        mx[r] = m; ss[r] = s;
    }
    #pragma unroll
    for (int k = 1; k < 16; k <<= 1) {
        #pragma unroll
        for (int r = 0; r < 4; r++) {
            float om = __shfl_xor(mx[r], k, 64);
            float os = __shfl_xor(ss[r], k, 64);
            float nm = fmaxf(mx[r], om);
            ss[r] = ss[r] * __expf(mx[r] - nm) + os * __expf(om - nm);
            mx[r] = nm;
            cxl_lab[r] = fmaxf(cxl_lab[r], __shfl_xor(cxl_lab[r], k, 64));
        }
    }

    // ---- epilogue: lanes with cn<4 each finalize one pixel (row g*4+cn) ----
    float v_nll = 0.f, v_ent = 0.f, valid = 0.f;
    if (cn < 4) {
        float m_s = sel4(mx, cn), s_s = sel4(ss, cn);
        float lse = m_s + __logf(s_s);
        float cxl = sel4(cxl_lab, cn);
        float xts = sel4(xtr, cn);
        int lb = cn == 0 ? labr[0] : cn == 1 ? labr[1] : cn == 2 ? labr[2] : labr[3];
        int pr = wavebase + g * 4 + cn;
        float z = fmaxf(cxl, 1.f + EPSF);
        float l_lab = -LOGIT_SCALE * __logf(z + sqrtf(fmaf(z, z, -1.f)));
        float nll = lse - l_lab;
        float pt = wsro[YT_OFF + lb], pn = wsro[XN_OFF + lb], ap = wsro[AP_OFF + lb];
        float num = fmaf(-cxl, pt, xts);                       // y_time + c_xyl*x_time
        float den = pn * sqrtf(fmaxf(fmaf(cxl, cxl, -1.f), 0.f));
        float ain = num / (den + EPSF);
        ain = fminf(fmaxf(ain, -1.f + EPSF), 1.f - EPSF);
        float ent = fmaxf(acosf(ain) - ap, 0.f);
        valid = mask[pr] ? 0.f : 1.f;
        v_nll = nll * valid;
        v_ent = ent * valid;
    }

    // ---- wave + block reduce, 3 atomics per block ----
    #pragma unroll
    for (int o = 32; o >= 1; o >>= 1) {
        v_nll += __shfl_down(v_nll, o, 64);
        v_ent += __shfl_down(v_ent, o, 64);
        valid += __shfl_down(valid, o, 64);
    }
    __shared__ float red[3][4];
    if (lane == 0) { red[0][wid] = v_nll; red[1][wid] = v_ent; red[2][wid] = valid; }
    __syncthreads();
    if (threadIdx.x == 0) {
        float a = 0.f, b = 0.f, c = 0.f;
        #pragma unroll
        for (int w = 0; w < 4; w++) { a += red[0][w]; b += red[1][w]; c += red[2][w]; }
        atomicAdd(&acc[0], a);
        atomicAdd(&acc[1], b);
        atomicAdd(&acc[2], c);
    }
}

__global__ void final_kernel(const float* acc, float* out) {
    float n = fmaxf(acc[2], 1.0f);
    out[0] = acc[0] / n + ENTAIL_WEIGHT * (acc[1] / n);
}

extern "C" void kernel_launch(void* const* d_in, const int* in_sizes, int n_in,
                              void* d_out, int out_size, void* d_ws, size_t ws_size,
                              hipStream_t stream) {
    const float* feats  = (const float*)d_in[0];
    const float* protos = (const float*)d_in[1];
    const int* labels   = (const int*)d_in[2];
    const unsigned char* mask = (const unsigned char*)d_in[3];  // numpy bool = 1 byte
    float* ws = (float*)d_ws;

    hipMemsetAsync(ws, 0, 16 * sizeof(float), stream);
    proto_kernel<<<NPAD, DIM, 0, stream>>>(protos, ws);

    int npix = in_sizes[2];                 // B*H*W = 524288
    int nblk = npix / 64;                   // 4 waves/block, 16 pixels/wave
    main_kernel<<<nblk, 256, 0, stream>>>(feats, labels, mask, ws, ws);
    final_kernel<<<1, 1, 0, stream>>>(ws, (float*)d_out);
}